// Round 17
// baseline (130.420 us; speedup 1.0000x reference)
//
#include <hip/hip_runtime.h>
#include <hip/hip_fp16.h>

#define NU 120000
#define NI 80000
#define NN 200000
#define DD 64
#define NE 1280000
#define BB 4096
#define NS 8192    // 2*B sampled nodes
#define NB2 196    // ceil(NN/1024) buckets, bucket = dst>>10
#define BCAP 8192  // slack capacity per bucket segment (mean 6530, +20 sigma)
#define CH2 2048   // coarse chunk; 625*2048 == NE exactly (no bounds checks)
#define CB 625

// fine4m mega-kernel block partition
#define FB 196
#define CONVB 3125     // conv blocks = NN*16/(256*4)
#define PREPB 64
#define BSB 32
// prop1 mega-kernel partition
#define P1B 2048
#define NLB 32         // NS/256

// 256-thread inclusive scan via wave shuffles: 6 shfl + 2 barriers (vs 16 barriers)
// returns inclusive scan of x; wsum is 4-int LDS scratch
__device__ __forceinline__ int scan256(int x, int* wsum) {
  int lane = threadIdx.x & 63, wv = threadIdx.x >> 6;
  int xs = x;
#pragma unroll
  for (int off = 1; off < 64; off <<= 1) {
    int v = __shfl_up(xs, off);
    if (lane >= off) xs += v;
  }
  if (lane == 63) wsum[wv] = xs;
  __syncthreads();
  int woff = 0;
  if (wv > 0) woff += wsum[0];
  if (wv > 1) woff += wsum[1];
  if (wv > 2) woff += wsum[2];
  __syncthreads();  // protect wsum for any subsequent scan
  return xs + woff;
}

// ---------------- pre: zero cursors/counters ----------------
__global__ void k_pre(int* __restrict__ bcur, int* __restrict__ n2cnt) {
  int t = threadIdx.x;
  if (t < NB2) bcur[t] = 0;
  if (t == 0) *n2cnt = 0;
}

// ---------------- coarse: LDS counting-sort of 2048 edges into 196 buckets ----------------
__global__ void k_coarse2(const int* __restrict__ src, const int* __restrict__ dst,
                          const float* __restrict__ val, int* __restrict__ bcur,
                          int2* __restrict__ c_sv) {
  __shared__ int2 sv[CH2];             // 16KB sorted staging
  __shared__ unsigned char map8[CH2];  // slot -> bucket
  __shared__ int hist[256];
  __shared__ int lbase[256];
  __shared__ int gbase[256];
  __shared__ int wsum[4];
  int t = threadIdx.x;
  hist[t] = 0;
  __syncthreads();
  int e0 = blockIdx.x * CH2;
  int d_[CH2 / 256];
#pragma unroll
  for (int k = 0; k < CH2 / 256; ++k) {
    int e = e0 + k * 256 + t;
    d_[k] = dst[e];
    atomicAdd(&hist[d_[k] >> 10], 1);
  }
  __syncthreads();
  int x = hist[t];
  int incl = scan256(x, wsum);
  int lb = incl - x;
  lbase[t] = lb;
  gbase[t] = (x && t < NB2) ? (t * BCAP + atomicAdd(&bcur[t], x)) : 0;
  for (int k = lb; k < lb + x; ++k) map8[k] = (unsigned char)t;
  hist[t] = 0;  // reuse as in-block cursor
  __syncthreads();
#pragma unroll
  for (int k = 0; k < CH2 / 256; ++k) {
    int e = e0 + k * 256 + t;
    int b = d_[k] >> 10;
    int lp = lbase[b] + atomicAdd(&hist[b], 1);
    sv[lp] = make_int2(src[e] | ((d_[k] & 1023) << 18), __float_as_int(val[e]));
  }
  __syncthreads();
  for (int sidx = t; sidx < CH2; sidx += 256) {
    int b = map8[sidx];
    c_sv[(size_t)gbase[b] + sidx - lbase[b]] = sv[sidx];  // coalesced runs
  }
}

// ---------------- device bodies for fine4m ----------------
__device__ __forceinline__ void d_conv(int rel, const float4* __restrict__ U4,
                                       const float4* __restrict__ V4, uint2* __restrict__ H0) {
  int t = threadIdx.x;
  float4 r[4];
#pragma unroll
  for (int k = 0; k < 4; ++k) {
    int idx = rel * 1024 + k * 256 + t;
    int node = idx >> 4, q = idx & 15;
    r[k] = (node < NU) ? U4[(size_t)node * 16 + q] : V4[(size_t)(node - NU) * 16 + q];
  }
#pragma unroll
  for (int k = 0; k < 4; ++k) {
    int idx = rel * 1024 + k * 256 + t;
    __half2 a = __floats2half2_rn(r[k].x, r[k].y);
    __half2 b = __floats2half2_rn(r[k].z, r[k].w);
    uint2 o;
    o.x = __builtin_bit_cast(unsigned int, a);
    o.y = __builtin_bit_cast(unsigned int, b);
    H0[idx] = o;
  }
}

__device__ __forceinline__ void d_prep(int rel, const float* __restrict__ Wq,
                                       const float* __restrict__ Wk, const float* __restrict__ Wv,
                                       const float* __restrict__ Wo, float* __restrict__ Mt,
                                       float* __restrict__ P) {
  int t = rel * 256 + threadIdx.x;
  if (t < 8192) {
    int h = t >> 12;
    int b = (t >> 6) & 63;
    int j = t & 63;
    float s = 0.f;
    for (int k = 0; k < 32; ++k) s += Wk[j * 64 + h * 32 + k] * Wq[b * 64 + h * 32 + k];
    Mt[h * 4096 + b * 64 + j] = s;
  } else if (t < 16384) {
    int t2 = t - 8192;
    int h = t2 >> 12;
    int d = (t2 >> 6) & 63;
    int j = t2 & 63;
    float s = 0.f;
    for (int v = 0; v < 32; ++v) s += Wv[d * 64 + h * 32 + v] * Wo[(h * 32 + v) * 64 + j];
    P[h * 4096 + d * 64 + j] = s;
  }
}

// ---------------- FINE4M mega-kernel: fine4b | conv | prep | build_s ----------------
__global__ void k_fine4m(const int* __restrict__ bcur, const int2* __restrict__ c_sv,
                         int2* __restrict__ pairs, int* __restrict__ row_ptr,
                         const float4* __restrict__ U4, const float4* __restrict__ V4,
                         uint2* __restrict__ H0, const float* __restrict__ Wq,
                         const float* __restrict__ Wk, const float* __restrict__ Wv,
                         const float* __restrict__ Wo, float* __restrict__ Mt,
                         float* __restrict__ P, const int* __restrict__ u,
                         const int* __restrict__ ii, int* __restrict__ snodes) {
  __shared__ int cnt[1024];
  __shared__ int pre[1024];
  __shared__ int cur[1024];
  __shared__ int bs[256];
  __shared__ int wsum[4];
  int b = blockIdx.x, t = threadIdx.x;
  if (b >= FB) {
    int r = b - FB;
    if (r < CONVB) {
      d_conv(r, U4, V4, H0);
    } else if (r < CONVB + PREPB) {
      d_prep(r - CONVB, Wq, Wk, Wv, Wo, Mt, P);
    } else {
      int tt = (r - CONVB - PREPB) * 256 + t;
      if (tt < NS) snodes[tt] = (tt < BB) ? u[tt] : NU + ii[tt - BB];
    }
    return;
  }
  // ---- fine4b body: one block per bucket ----
  int bc = (t < NB2) ? bcur[t] : 0;
  bs[t] = scan256(bc, wsum);  // inclusive over bucket counts
  __syncthreads();
  int segN = bcur[b];
  int out0 = bs[b] - segN;
  int seg0 = b * BCAP;
  for (int k = t; k < 1024; k += 256) cnt[k] = 0;
  __syncthreads();
  for (int e = t; e < segN; e += 256) atomicAdd(&cnt[(c_sv[seg0 + e].x >> 18) & 1023], 1);
  __syncthreads();
  int a0 = cnt[4 * t], a1 = cnt[4 * t + 1], a2 = cnt[4 * t + 2], a3 = cnt[4 * t + 3];
  int tot = a0 + a1 + a2 + a3;
  int incl = scan256(tot, wsum);
  int base = incl - tot;
  pre[4 * t] = base;
  pre[4 * t + 1] = base + a0;
  pre[4 * t + 2] = base + a0 + a1;
  pre[4 * t + 3] = base + a0 + a1 + a2;
  int node0 = b << 10;
#pragma unroll
  for (int k = 0; k < 4; ++k) {
    int n = node0 + 4 * t + k;
    if (n < NN) row_ptr[n] = out0 + pre[4 * t + k];
  }
  if (b == 0 && t == 0) row_ptr[NN] = NE;
  for (int k = t; k < 1024; k += 256) cur[k] = 0;
  __syncthreads();
  for (int e = t; e < segN; e += 256) {
    int2 svv = c_sv[seg0 + e];
    int ld = (svv.x >> 18) & 1023;
    int off = atomicAdd(&cur[ld], 1);
    pairs[out0 + pre[ld] + off] = make_int2(svv.x & 0x3FFFF, svv.y);
  }
}

// ---------------- propagation: 16-lane group per node, fp16 in, fp32 acc ----------------
template <int ULIST>
__device__ __forceinline__ void d_prop(const uint2* __restrict__ Hin, uint2* __restrict__ Hout,
                                       const int* __restrict__ row_ptr,
                                       const int2* __restrict__ pairs,
                                       const int* __restrict__ list,
                                       const int* __restrict__ countp, int cconst, int relbid,
                                       int nblk) {
  int n = countp ? *countp : cconst;
  int lane = threadIdx.x & 63;
  int c = lane & 15;
  int sl = c & 7;
  int gstride = (nblk * 256) >> 4;
  for (int gid = (relbid * 256 + (int)threadIdx.x) >> 4; gid < n; gid += gstride) {
    int node = ULIST ? list[gid] : gid;
    int start = row_ptr[node], end = row_ptr[node + 1];
    float4 acc = make_float4(0.f, 0.f, 0.f, 0.f);
    for (int t0 = start; t0 < end; t0 += 8) {
      int cap = end - t0;
      if (cap > 8) cap = 8;
      int2 mp = pairs[t0 + (sl < cap ? sl : 0)];  // coalesced tile-index load
      uint2 r[8];
      float vv[8];
#pragma unroll
      for (int k = 0; k < 8; ++k) {
        int srclane = (lane & 48) + k;
        int sidx = __shfl(mp.x, srclane);
        float v = __int_as_float(__shfl(mp.y, srclane));
        vv[k] = (k < cap) ? v : 0.f;
        r[k] = Hin[(size_t)sidx * 16 + c];  // 8 independent 8B gathers in flight
      }
#pragma unroll
      for (int k = 0; k < 8; ++k) {
        float2 f0 = __half22float2(__builtin_bit_cast(__half2, r[k].x));
        float2 f1 = __half22float2(__builtin_bit_cast(__half2, r[k].y));
        acc.x += vv[k] * f0.x;
        acc.y += vv[k] * f0.y;
        acc.z += vv[k] * f1.x;
        acc.w += vv[k] * f1.y;
      }
    }
    __half2 a = __floats2half2_rn(acc.x, acc.y);
    __half2 bq = __floats2half2_rn(acc.z, acc.w);
    uint2 o;
    o.x = __builtin_bit_cast(unsigned int, a);
    o.y = __builtin_bit_cast(unsigned int, bq);
    Hout[(size_t)node * 16 + c] = o;
  }
}

// ---------------- PROP1 mega-kernel: prop1-all | nbrlist ----------------
__global__ void k_prop1m(const uint2* __restrict__ H0, uint2* __restrict__ H1,
                         const int* __restrict__ snodes, const int* __restrict__ row_ptr,
                         const int2* __restrict__ pairs, int* __restrict__ n2list,
                         int* __restrict__ n2cnt) {
  int b = blockIdx.x;
  if (b < P1B) {
    d_prop<0>(H0, H1, row_ptr, pairs, nullptr, nullptr, NN, b, P1B);
  } else {
    int idx = (b - P1B) * 256 + threadIdx.x;
    if (idx < NS) {
      int node = snodes[idx];
      int s0 = row_ptr[node], e0 = row_ptr[node + 1];
      int pos = atomicAdd(n2cnt, e0 - s0 + 1);
      n2list[pos++] = node;
      for (int j = s0; j < e0; ++j) n2list[pos++] = pairs[j].x;
    }
  }
}

// ---------------- STAGE2: prop2 over n2list (dupes benign) ----------------
__global__ void k_stage2(const uint2* __restrict__ H1, uint2* __restrict__ H2,
                         const int* __restrict__ row_ptr, const int2* __restrict__ pairs,
                         const int* __restrict__ n2list, const int* __restrict__ n2cnt) {
  d_prop<1>(H1, H2, row_ptr, pairs, n2list, n2cnt, 0, blockIdx.x, 2048);
}

// ---------------- fused attention + inline E3-prop + pair scoring ----------------
__global__ void k_attn4(const float* __restrict__ Uf, const float* __restrict__ Vf,
                        const __half* __restrict__ H1h, const __half* __restrict__ H2h,
                        const int* __restrict__ snodes, const int* __restrict__ row_ptr,
                        const int2* __restrict__ pairs, const float* __restrict__ Mt,
                        const float* __restrict__ P, float* __restrict__ out) {
  __shared__ float sb[4][3 * 64];
  int wv = threadIdx.x >> 6, lane = threadIdx.x & 63;
  int w = blockIdx.x * 4 + wv;
  if (w >= BB) return;
  const float inv_scale = 0.17677669529663687f;  // 1/sqrt(32)
  const float* M0 = Mt;
  const float* M1 = Mt + 4096;
  const float* P0 = P;
  const float* P1 = P + 4096;
  float eo[2];
#pragma unroll
  for (int side = 0; side < 2; ++side) {
    int p = side ? (BB + w) : w;
    int node = snodes[p];
    float e0 = (node < NU) ? Uf[(size_t)node * DD + lane] : Vf[(size_t)(node - NU) * DD + lane];
    float e1 = __half2float(H1h[(size_t)node * DD + lane]);
    float e2 = __half2float(H2h[(size_t)node * DD + lane]);

    // e3 = (A @ H2)[node] computed inline (same tile-8 order as d_prop)
    float e3 = 0.f;
    {
      int start = row_ptr[node], end = row_ptr[node + 1];
      int sl = lane & 7;
      for (int t0 = start; t0 < end; t0 += 8) {
        int cap = end - t0;
        if (cap > 8) cap = 8;
        int2 mp = pairs[t0 + (sl < cap ? sl : 0)];
        __half r[8];
        float vv[8];
#pragma unroll
        for (int k = 0; k < 8; ++k) {
          int sidx = __shfl(mp.x, k);
          float v = __int_as_float(__shfl(mp.y, k));
          vv[k] = (k < cap) ? v : 0.f;
          r[k] = H2h[(size_t)sidx * DD + lane];  // 8 independent row loads
        }
#pragma unroll
        for (int k = 0; k < 8; ++k) e3 += vv[k] * __half2float(r[k]);
      }
    }
    sb[wv][lane] = e0;

    float g0 = 0.f, g1 = 0.f;
#pragma unroll 8
    for (int b = 0; b < 64; ++b) {
      float eb = sb[wv][b];  // LDS same-address broadcast (wave-synchronous)
      g0 = fmaf(M0[b * 64 + lane], eb, g0);
      g1 = fmaf(M1[b * 64 + lane], eb, g1);
    }

    float el[4] = {e0, e1, e2, e3};
    float sc[4][2];
#pragma unroll
    for (int l = 0; l < 4; ++l) {
      float p0 = el[l] * g0, p1 = el[l] * g1;
#pragma unroll
      for (int o = 32; o; o >>= 1) {
        p0 += __shfl_xor(p0, o);
        p1 += __shfl_xor(p1, o);
      }
      sc[l][0] = p0 * inv_scale;
      sc[l][1] = p1 * inv_scale;
    }

    float ebar[2];
#pragma unroll
    for (int h = 0; h < 2; ++h) {
      float m = fmaxf(fmaxf(sc[0][h], sc[1][h]), fmaxf(sc[2][h], sc[3][h]));
      float x0 = expf(sc[0][h] - m), x1 = expf(sc[1][h] - m);
      float x2 = expf(sc[2][h] - m), x3 = expf(sc[3][h] - m);
      float inv = 1.f / (x0 + x1 + x2 + x3);
      ebar[h] = (x0 * e0 + x1 * e1 + x2 * e2 + x3 * e3) * inv;
    }
    sb[wv][64 + lane] = ebar[0];
    sb[wv][128 + lane] = ebar[1];

    float o = 0.f;
#pragma unroll 8
    for (int d = 0; d < 64; ++d) {
      float b0 = sb[wv][64 + d];
      float b1 = sb[wv][128 + d];
      o = fmaf(P0[d * 64 + lane], b0, o);
      o = fmaf(P1[d * 64 + lane], b1, o);
    }
    eo[side] = o;
  }
  float pd = eo[0] * eo[1];
#pragma unroll
  for (int o = 32; o; o >>= 1) pd += __shfl_xor(pd, o);
  if (lane == 0) out[w] = pd;
}

extern "C" void kernel_launch(void* const* d_in, const int* in_sizes, int n_in,
                              void* d_out, int out_size, void* d_ws, size_t ws_size,
                              hipStream_t stream) {
  const int* edge_src = (const int*)d_in[0];
  const int* edge_dst = (const int*)d_in[1];
  const float* edge_val = (const float*)d_in[2];
  const float* U_emb = (const float*)d_in[3];
  const float* V_emb = (const float*)d_in[4];
  const float* Wq = (const float*)d_in[5];
  const float* Wk = (const float*)d_in[6];
  const float* Wv = (const float*)d_in[7];
  const float* Wo = (const float*)d_in[8];
  const int* u = (const int*)d_in[9];
  const int* ii = (const int*)d_in[10];
  float* out = (float*)d_out;

  const float4* U4 = (const float4*)U_emb;
  const float4* V4 = (const float4*)V_emb;

  // workspace layout (16B-aligned base)
  float* Ea = (float*)d_ws;                          // H0 | H1 (fp16 tables, 25.6MB each)
  float* Eb = Ea + (size_t)NN * DD;                  // H2 (aliases c_sv scratch before)
  float* Es = Eb + (size_t)NN * DD;                  // n2list scratch region
  float* Mt = Es + (size_t)4 * NS * DD;              // 2*4096
  float* Pm = Mt + 8192;                             // 2*4096
  int* row_ptr = (int*)(Pm + 8192);                  // NN+1 (+pad)
  int* bcur = row_ptr + NN + 4;                      // NB2
  int* snodes = bcur + NB2;                          // NS
  int* n2cnt = snodes + NS;                          // 1
  uintptr_t pa = (uintptr_t)(n2cnt + 1);
  pa = (pa + 15) & ~(uintptr_t)15;
  int2* pairs = (int2*)pa;                           // NE int2

  uint2* H0 = (uint2*)Ea;                 // NN*16 uint2
  uint2* H1 = H0 + (size_t)NN * 16;
  uint2* H2 = (uint2*)Eb;                 // written after c_sv dead
  int2* c_sv = (int2*)Eb;                 // NB2*BCAP int2 = 12.8MB — dead after k_fine4m
  int* n2list = (int*)Es;                 // Es region (no other use)

  k_pre<<<1, 256, 0, stream>>>(bcur, n2cnt);
  k_coarse2<<<CB, 256, 0, stream>>>(edge_src, edge_dst, edge_val, bcur, c_sv);
  k_fine4m<<<FB + CONVB + PREPB + BSB, 256, 0, stream>>>(bcur, c_sv, pairs, row_ptr, U4, V4, H0,
                                                         Wq, Wk, Wv, Wo, Mt, Pm, u, ii, snodes);
  k_prop1m<<<P1B + NLB, 256, 0, stream>>>(H0, H1, snodes, row_ptr, pairs, n2list, n2cnt);
  k_stage2<<<2048, 256, 0, stream>>>(H1, H2, row_ptr, pairs, n2list, n2cnt);
  k_attn4<<<(BB + 3) / 4, 256, 0, stream>>>(U_emb, V_emb, (const __half*)H1, (const __half*)H2,
                                            snodes, row_ptr, pairs, Mt, Pm, out);
}

// Round 18
// 127.955 us; speedup vs baseline: 1.0193x; 1.0193x over previous
//
#include <hip/hip_runtime.h>
#include <hip/hip_fp16.h>

#define NU 120000
#define NI 80000
#define NN 200000
#define DD 64
#define NE 1280000
#define BB 4096
#define NS 8192    // 2*B sampled nodes
#define NB2 196    // ceil(NN/1024) buckets, bucket = dst>>10
#define BCAP 8192  // slack capacity per bucket segment (mean 6530, +20 sigma)
#define CH2 4096   // coarse chunk
#define CB 313     // ceil(NE/CH2)

// fine4m mega-kernel block partition
#define FB 196
#define CONVB 3125     // conv blocks = NN*16/(256*4)
#define PREPB 64
#define BSB 32
// prop1 mega-kernel partition
#define P1B 2048
#define NLB 32         // NS/256

// ---------------- pre: zero cursors/counters ----------------
__global__ void k_pre(int* __restrict__ bcur, int* __restrict__ n2cnt) {
  int t = threadIdx.x;
  if (t < NB2) bcur[t] = 0;
  if (t == 0) *n2cnt = 0;
}

// ---------------- coarse: LDS counting-sort of 4096 edges into 196 buckets ----------------
__global__ void k_coarse2(const int* __restrict__ src, const int* __restrict__ dst,
                          const float* __restrict__ val, int* __restrict__ bcur,
                          int2* __restrict__ c_sv) {
  __shared__ int2 sv[CH2];             // 32KB sorted staging
  __shared__ unsigned char map8[CH2];  // slot -> bucket
  __shared__ int hist[256];
  __shared__ int lbase[256];
  __shared__ int gbase[256];
  __shared__ int s[256];
  int t = threadIdx.x;
  hist[t] = 0;
  __syncthreads();
  int e0 = blockIdx.x * CH2;
  int d_[CH2 / 256];
#pragma unroll
  for (int k = 0; k < CH2 / 256; ++k) {
    int e = e0 + k * 256 + t;
    d_[k] = (e < NE) ? dst[e] : -1;
    if (d_[k] >= 0) atomicAdd(&hist[d_[k] >> 10], 1);
  }
  __syncthreads();
  int x = hist[t];
  s[t] = x;
  __syncthreads();
  for (int off = 1; off < 256; off <<= 1) {
    int v = (t >= off) ? s[t - off] : 0;
    __syncthreads();
    s[t] += v;
    __syncthreads();
  }
  int lb = s[t] - x;
  lbase[t] = lb;
  gbase[t] = (x && t < NB2) ? (t * BCAP + atomicAdd(&bcur[t], x)) : 0;
  for (int k = lb; k < lb + x; ++k) map8[k] = (unsigned char)t;
  hist[t] = 0;  // reuse as in-block cursor
  __syncthreads();
#pragma unroll
  for (int k = 0; k < CH2 / 256; ++k) {
    int e = e0 + k * 256 + t;
    if (d_[k] >= 0) {
      int b = d_[k] >> 10;
      int lp = lbase[b] + atomicAdd(&hist[b], 1);
      sv[lp] = make_int2(src[e] | ((d_[k] & 1023) << 18), __float_as_int(val[e]));
    }
  }
  __syncthreads();
  int nval = NE - e0;
  if (nval > CH2) nval = CH2;
  for (int sidx = t; sidx < nval; sidx += 256) {
    int b = map8[sidx];
    c_sv[(size_t)gbase[b] + sidx - lbase[b]] = sv[sidx];  // coalesced runs
  }
}

// ---------------- device bodies for fine4m ----------------
__device__ __forceinline__ void d_conv(int rel, const float4* __restrict__ U4,
                                       const float4* __restrict__ V4, uint2* __restrict__ H0) {
  int t = threadIdx.x;
  float4 r[4];
#pragma unroll
  for (int k = 0; k < 4; ++k) {
    int idx = rel * 1024 + k * 256 + t;
    int node = idx >> 4, q = idx & 15;
    r[k] = (node < NU) ? U4[(size_t)node * 16 + q] : V4[(size_t)(node - NU) * 16 + q];
  }
#pragma unroll
  for (int k = 0; k < 4; ++k) {
    int idx = rel * 1024 + k * 256 + t;
    __half2 a = __floats2half2_rn(r[k].x, r[k].y);
    __half2 b = __floats2half2_rn(r[k].z, r[k].w);
    uint2 o;
    o.x = __builtin_bit_cast(unsigned int, a);
    o.y = __builtin_bit_cast(unsigned int, b);
    H0[idx] = o;
  }
}

__device__ __forceinline__ void d_prep(int rel, const float* __restrict__ Wq,
                                       const float* __restrict__ Wk, const float* __restrict__ Wv,
                                       const float* __restrict__ Wo, float* __restrict__ Mt,
                                       float* __restrict__ P) {
  int t = rel * 256 + threadIdx.x;
  if (t < 8192) {
    int h = t >> 12;
    int b = (t >> 6) & 63;
    int j = t & 63;
    float s = 0.f;
    for (int k = 0; k < 32; ++k) s += Wk[j * 64 + h * 32 + k] * Wq[b * 64 + h * 32 + k];
    Mt[h * 4096 + b * 64 + j] = s;
  } else if (t < 16384) {
    int t2 = t - 8192;
    int h = t2 >> 12;
    int d = (t2 >> 6) & 63;
    int j = t2 & 63;
    float s = 0.f;
    for (int v = 0; v < 32; ++v) s += Wv[d * 64 + h * 32 + v] * Wo[(h * 32 + v) * 64 + j];
    P[h * 4096 + d * 64 + j] = s;
  }
}

// ---------------- FINE4M mega-kernel: fine4b | conv | prep | build_s ----------------
__global__ void k_fine4m(const int* __restrict__ bcur, const int2* __restrict__ c_sv,
                         int2* __restrict__ pairs, int* __restrict__ row_ptr,
                         const float4* __restrict__ U4, const float4* __restrict__ V4,
                         uint2* __restrict__ H0, const float* __restrict__ Wq,
                         const float* __restrict__ Wk, const float* __restrict__ Wv,
                         const float* __restrict__ Wo, float* __restrict__ Mt,
                         float* __restrict__ P, const int* __restrict__ u,
                         const int* __restrict__ ii, int* __restrict__ snodes) {
  __shared__ int cnt[1024];
  __shared__ int pre[1024];
  __shared__ int cur[1024];
  __shared__ int s[256];
  __shared__ int bs[256];
  int b = blockIdx.x, t = threadIdx.x;
  if (b >= FB) {
    int r = b - FB;
    if (r < CONVB) {
      d_conv(r, U4, V4, H0);
    } else if (r < CONVB + PREPB) {
      d_prep(r - CONVB, Wq, Wk, Wv, Wo, Mt, P);
    } else {
      int tt = (r - CONVB - PREPB) * 256 + t;
      if (tt < NS) snodes[tt] = (tt < BB) ? u[tt] : NU + ii[tt - BB];
    }
    return;
  }
  // ---- fine4b body: one block per bucket ----
  int bc = (t < NB2) ? bcur[t] : 0;
  bs[t] = bc;
  __syncthreads();
  for (int off = 1; off < 256; off <<= 1) {
    int v = (t >= off) ? bs[t - off] : 0;
    __syncthreads();
    bs[t] += v;
    __syncthreads();
  }
  int segN = bcur[b];
  int out0 = bs[b] - segN;
  int seg0 = b * BCAP;
  for (int k = t; k < 1024; k += 256) cnt[k] = 0;
  __syncthreads();
  for (int e = t; e < segN; e += 256) atomicAdd(&cnt[(c_sv[seg0 + e].x >> 18) & 1023], 1);
  __syncthreads();
  int a0 = cnt[4 * t], a1 = cnt[4 * t + 1], a2 = cnt[4 * t + 2], a3 = cnt[4 * t + 3];
  int tot = a0 + a1 + a2 + a3;
  s[t] = tot;
  __syncthreads();
  for (int off = 1; off < 256; off <<= 1) {
    int v = (t >= off) ? s[t - off] : 0;
    __syncthreads();
    s[t] += v;
    __syncthreads();
  }
  int base = s[t] - tot;
  pre[4 * t] = base;
  pre[4 * t + 1] = base + a0;
  pre[4 * t + 2] = base + a0 + a1;
  pre[4 * t + 3] = base + a0 + a1 + a2;
  int node0 = b << 10;
#pragma unroll
  for (int k = 0; k < 4; ++k) {
    int n = node0 + 4 * t + k;
    if (n < NN) row_ptr[n] = out0 + pre[4 * t + k];
  }
  if (b == 0 && t == 0) row_ptr[NN] = NE;
  for (int k = t; k < 1024; k += 256) cur[k] = 0;
  __syncthreads();
  for (int e = t; e < segN; e += 256) {
    int2 svv = c_sv[seg0 + e];
    int ld = (svv.x >> 18) & 1023;
    int off = atomicAdd(&cur[ld], 1);
    pairs[out0 + pre[ld] + off] = make_int2(svv.x & 0x3FFFF, svv.y);
  }
}

// ---------------- propagation: 16-lane group per node, fp16 in, fp32 acc ----------------
template <int ULIST>
__device__ __forceinline__ void d_prop(const uint2* __restrict__ Hin, uint2* __restrict__ Hout,
                                       const int* __restrict__ row_ptr,
                                       const int2* __restrict__ pairs,
                                       const int* __restrict__ list,
                                       const int* __restrict__ countp, int cconst, int relbid,
                                       int nblk) {
  int n = countp ? *countp : cconst;
  int lane = threadIdx.x & 63;
  int c = lane & 15;
  int sl = c & 7;
  int gstride = (nblk * 256) >> 4;
  for (int gid = (relbid * 256 + (int)threadIdx.x) >> 4; gid < n; gid += gstride) {
    int node = ULIST ? list[gid] : gid;
    int start = row_ptr[node], end = row_ptr[node + 1];
    float4 acc = make_float4(0.f, 0.f, 0.f, 0.f);
    for (int t0 = start; t0 < end; t0 += 8) {
      int cap = end - t0;
      if (cap > 8) cap = 8;
      int2 mp = pairs[t0 + (sl < cap ? sl : 0)];  // coalesced tile-index load
      uint2 r[8];
      float vv[8];
#pragma unroll
      for (int k = 0; k < 8; ++k) {
        int srclane = (lane & 48) + k;
        int sidx = __shfl(mp.x, srclane);
        float v = __int_as_float(__shfl(mp.y, srclane));
        vv[k] = (k < cap) ? v : 0.f;
        r[k] = Hin[(size_t)sidx * 16 + c];  // 8 independent 8B gathers in flight
      }
#pragma unroll
      for (int k = 0; k < 8; ++k) {
        float2 f0 = __half22float2(__builtin_bit_cast(__half2, r[k].x));
        float2 f1 = __half22float2(__builtin_bit_cast(__half2, r[k].y));
        acc.x += vv[k] * f0.x;
        acc.y += vv[k] * f0.y;
        acc.z += vv[k] * f1.x;
        acc.w += vv[k] * f1.y;
      }
    }
    __half2 a = __floats2half2_rn(acc.x, acc.y);
    __half2 bq = __floats2half2_rn(acc.z, acc.w);
    uint2 o;
    o.x = __builtin_bit_cast(unsigned int, a);
    o.y = __builtin_bit_cast(unsigned int, bq);
    Hout[(size_t)node * 16 + c] = o;
  }
}

// ---------------- PROP1 mega-kernel: prop1-all | nbrlist ----------------
__global__ void k_prop1m(const uint2* __restrict__ H0, uint2* __restrict__ H1,
                         const int* __restrict__ snodes, const int* __restrict__ row_ptr,
                         const int2* __restrict__ pairs, int* __restrict__ n2list,
                         int* __restrict__ n2cnt) {
  int b = blockIdx.x;
  if (b < P1B) {
    d_prop<0>(H0, H1, row_ptr, pairs, nullptr, nullptr, NN, b, P1B);
  } else {
    int idx = (b - P1B) * 256 + threadIdx.x;
    if (idx < NS) {
      int node = snodes[idx];
      int s0 = row_ptr[node], e0 = row_ptr[node + 1];
      int pos = atomicAdd(n2cnt, e0 - s0 + 1);
      n2list[pos++] = node;
      for (int j = s0; j < e0; ++j) n2list[pos++] = pairs[j].x;
    }
  }
}

// ---------------- STAGE2: prop2 over n2list (dupes benign) ----------------
__global__ void k_stage2(const uint2* __restrict__ H1, uint2* __restrict__ H2,
                         const int* __restrict__ row_ptr, const int2* __restrict__ pairs,
                         const int* __restrict__ n2list, const int* __restrict__ n2cnt) {
  d_prop<1>(H1, H2, row_ptr, pairs, n2list, n2cnt, 0, blockIdx.x, 1536);
}

// ---------------- fused attention + inline E3-prop + pair scoring ----------------
__global__ void k_attn4(const float* __restrict__ Uf, const float* __restrict__ Vf,
                        const __half* __restrict__ H1h, const __half* __restrict__ H2h,
                        const int* __restrict__ snodes, const int* __restrict__ row_ptr,
                        const int2* __restrict__ pairs, const float* __restrict__ Mt,
                        const float* __restrict__ P, float* __restrict__ out) {
  __shared__ float sb[4][3 * 64];
  int wv = threadIdx.x >> 6, lane = threadIdx.x & 63;
  int w = blockIdx.x * 4 + wv;
  if (w >= BB) return;
  const float inv_scale = 0.17677669529663687f;  // 1/sqrt(32)
  const float* M0 = Mt;
  const float* M1 = Mt + 4096;
  const float* P0 = P;
  const float* P1 = P + 4096;
  float eo[2];
#pragma unroll
  for (int side = 0; side < 2; ++side) {
    int p = side ? (BB + w) : w;
    int node = snodes[p];
    float e0 = (node < NU) ? Uf[(size_t)node * DD + lane] : Vf[(size_t)(node - NU) * DD + lane];
    float e1 = __half2float(H1h[(size_t)node * DD + lane]);
    float e2 = __half2float(H2h[(size_t)node * DD + lane]);

    // e3 = (A @ H2)[node] computed inline (same tile-8 order as d_prop)
    float e3 = 0.f;
    {
      int start = row_ptr[node], end = row_ptr[node + 1];
      int sl = lane & 7;
      for (int t0 = start; t0 < end; t0 += 8) {
        int cap = end - t0;
        if (cap > 8) cap = 8;
        int2 mp = pairs[t0 + (sl < cap ? sl : 0)];
        __half r[8];
        float vv[8];
#pragma unroll
        for (int k = 0; k < 8; ++k) {
          int sidx = __shfl(mp.x, k);
          float v = __int_as_float(__shfl(mp.y, k));
          vv[k] = (k < cap) ? v : 0.f;
          r[k] = H2h[(size_t)sidx * DD + lane];  // 8 independent row loads
        }
#pragma unroll
        for (int k = 0; k < 8; ++k) e3 += vv[k] * __half2float(r[k]);
      }
    }
    sb[wv][lane] = e0;

    float g0 = 0.f, g1 = 0.f;
#pragma unroll 8
    for (int b = 0; b < 64; ++b) {
      float eb = sb[wv][b];  // LDS same-address broadcast (wave-synchronous)
      g0 = fmaf(M0[b * 64 + lane], eb, g0);
      g1 = fmaf(M1[b * 64 + lane], eb, g1);
    }

    float el[4] = {e0, e1, e2, e3};
    float sc[4][2];
#pragma unroll
    for (int l = 0; l < 4; ++l) {
      float p0 = el[l] * g0, p1 = el[l] * g1;
#pragma unroll
      for (int o = 32; o; o >>= 1) {
        p0 += __shfl_xor(p0, o);
        p1 += __shfl_xor(p1, o);
      }
      sc[l][0] = p0 * inv_scale;
      sc[l][1] = p1 * inv_scale;
    }

    float ebar[2];
#pragma unroll
    for (int h = 0; h < 2; ++h) {
      float m = fmaxf(fmaxf(sc[0][h], sc[1][h]), fmaxf(sc[2][h], sc[3][h]));
      float x0 = expf(sc[0][h] - m), x1 = expf(sc[1][h] - m);
      float x2 = expf(sc[2][h] - m), x3 = expf(sc[3][h] - m);
      float inv = 1.f / (x0 + x1 + x2 + x3);
      ebar[h] = (x0 * e0 + x1 * e1 + x2 * e2 + x3 * e3) * inv;
    }
    sb[wv][64 + lane] = ebar[0];
    sb[wv][128 + lane] = ebar[1];

    float o = 0.f;
#pragma unroll 8
    for (int d = 0; d < 64; ++d) {
      float b0 = sb[wv][64 + d];
      float b1 = sb[wv][128 + d];
      o = fmaf(P0[d * 64 + lane], b0, o);
      o = fmaf(P1[d * 64 + lane], b1, o);
    }
    eo[side] = o;
  }
  float pd = eo[0] * eo[1];
#pragma unroll
  for (int o = 32; o; o >>= 1) pd += __shfl_xor(pd, o);
  if (lane == 0) out[w] = pd;
}

extern "C" void kernel_launch(void* const* d_in, const int* in_sizes, int n_in,
                              void* d_out, int out_size, void* d_ws, size_t ws_size,
                              hipStream_t stream) {
  const int* edge_src = (const int*)d_in[0];
  const int* edge_dst = (const int*)d_in[1];
  const float* edge_val = (const float*)d_in[2];
  const float* U_emb = (const float*)d_in[3];
  const float* V_emb = (const float*)d_in[4];
  const float* Wq = (const float*)d_in[5];
  const float* Wk = (const float*)d_in[6];
  const float* Wv = (const float*)d_in[7];
  const float* Wo = (const float*)d_in[8];
  const int* u = (const int*)d_in[9];
  const int* ii = (const int*)d_in[10];
  float* out = (float*)d_out;

  const float4* U4 = (const float4*)U_emb;
  const float4* V4 = (const float4*)V_emb;

  // workspace layout (16B-aligned base)
  float* Ea = (float*)d_ws;                          // H0 | H1 (fp16 tables, 25.6MB each)
  float* Eb = Ea + (size_t)NN * DD;                  // H2 (aliases c_sv scratch before)
  float* Es = Eb + (size_t)NN * DD;                  // n2list scratch region
  float* Mt = Es + (size_t)4 * NS * DD;              // 2*4096
  float* Pm = Mt + 8192;                             // 2*4096
  int* row_ptr = (int*)(Pm + 8192);                  // NN+1 (+pad)
  int* bcur = row_ptr + NN + 4;                      // NB2
  int* snodes = bcur + NB2;                          // NS
  int* n2cnt = snodes + NS;                          // 1
  uintptr_t pa = (uintptr_t)(n2cnt + 1);
  pa = (pa + 15) & ~(uintptr_t)15;
  int2* pairs = (int2*)pa;                           // NE int2

  uint2* H0 = (uint2*)Ea;                 // NN*16 uint2
  uint2* H1 = H0 + (size_t)NN * 16;
  uint2* H2 = (uint2*)Eb;                 // written after c_sv dead
  int2* c_sv = (int2*)Eb;                 // NB2*BCAP int2 = 12.8MB — dead after k_fine4m
  int* n2list = (int*)Es;                 // Es region (no other use)

  k_pre<<<1, 256, 0, stream>>>(bcur, n2cnt);
  k_coarse2<<<CB, 256, 0, stream>>>(edge_src, edge_dst, edge_val, bcur, c_sv);
  k_fine4m<<<FB + CONVB + PREPB + BSB, 256, 0, stream>>>(bcur, c_sv, pairs, row_ptr, U4, V4, H0,
                                                         Wq, Wk, Wv, Wo, Mt, Pm, u, ii, snodes);
  k_prop1m<<<P1B + NLB, 256, 0, stream>>>(H0, H1, snodes, row_ptr, pairs, n2list, n2cnt);
  k_stage2<<<1536, 256, 0, stream>>>(H1, H2, row_ptr, pairs, n2list, n2cnt);
  k_attn4<<<(BB + 3) / 4, 256, 0, stream>>>(U_emb, V_emb, (const __half*)H1, (const __half*)H2,
                                            snodes, row_ptr, pairs, Mt, Pm, out);
}